// Round 1
// baseline (940.948 us; speedup 1.0000x reference)
//
#include <hip/hip_runtime.h>
#include <math.h>

#define B_ 16
#define L_ 256
#define S_ 100
#define LA_ 48
#define NA_ 32
#define E_ 64
#define D_ 768
#define H_ 12
#define NHID_ 1024
#define WIDX_ 102
#define EPSF 1e-12f

// ---------------- meta: per-b sb, sls, last ----------------
__global__ void k_meta(const int* __restrict__ idxs, const int* __restrict__ blen,
                       int* __restrict__ meta) {
  int b = blockIdx.x, t = threadIdx.x;
  __shared__ int cnt;
  if (t == 0) cnt = 0;
  __syncthreads();
  if (t < WIDX_ && idxs[b * WIDX_ + t] > 0) atomicAdd(&cnt, 1);
  __syncthreads();
  if (t == 0) {
    int sb = cnt - 2;
    meta[b * 4 + 0] = sb;
    meta[b * 4 + 1] = idxs[b * WIDX_ + sb];  // sls
    meta[b * 4 + 2] = blen[b] - 1;           // last
  }
}

// ---------------- gather sent_emb (y<S) and arg_emb (y>=S) ----------------
__global__ void k_gather(const float* __restrict__ emb, const int* __restrict__ idxs,
                         const int* __restrict__ meta, float* __restrict__ sent_emb,
                         float* __restrict__ arg_emb) {
  int b = blockIdx.y, y = blockIdx.x, t = threadIdx.x;
  int sb = meta[b * 4 + 0], sls = meta[b * 4 + 1], last = meta[b * 4 + 2];
  if (y < S_) {
    int s = y;
    float* dst = sent_emb + ((size_t)b * S_ + s) * D_;
    if (s < sb) {
      const float* src = emb + ((size_t)b * L_ + idxs[b * WIDX_ + s]) * D_;
      for (int d = t; d < D_; d += 256) dst[d] = src[d];
    } else {
      for (int d = t; d < D_; d += 256) dst[d] = 0.f;
    }
  } else {
    int l = y - S_;
    int pos = sls + 1 + l;
    float* dst = arg_emb + ((size_t)b * LA_ + l) * D_;
    if (pos < last) {
      int p = pos > (L_ - 1) ? (L_ - 1) : pos;
      const float* src = emb + ((size_t)b * L_ + p) * D_;
      for (int d = t; d < D_; d += 256) dst[d] = src[d];
    } else {
      for (int d = t; d < D_; d += 256) dst[d] = 0.f;
    }
  }
}

// ---------------- trig: weighted mean over triggers ----------------
__global__ void k_trig(const float* __restrict__ sent_emb, const float* __restrict__ is_trig,
                       float* __restrict__ trig) {
  int b = blockIdx.y;
  int d = blockIdx.x * 256 + threadIdx.x;
  float acc = 0.f, den = 0.f;
  for (int s = 0; s < S_; s++) {
    float w = is_trig[b * S_ + s];
    den += w;
    if (w != 0.f) acc += w * sent_emb[((size_t)b * S_ + s) * D_ + d];
  }
  trig[b * D_ + d] = acc / den;
}

// ---------------- entity0 = ent_map^T @ sent_emb ; also e0*trig and nonempty ----------------
__global__ __launch_bounds__(256) void k_entity0(const float* __restrict__ sent_emb,
                                                 const float* __restrict__ ent_map,
                                                 const float* __restrict__ trig,
                                                 float* __restrict__ e0, float* __restrict__ e0t,
                                                 float* __restrict__ ne) {
  int b = blockIdx.y, e = blockIdx.x, t = threadIdx.x;
  float a0 = 0.f, a1 = 0.f, a2 = 0.f;
  for (int s = 0; s < S_; s++) {
    float w = ent_map[((size_t)b * S_ + s) * E_ + e];
    if (w != 0.f) {
      const float* r = sent_emb + ((size_t)b * S_ + s) * D_;
      a0 += w * r[t]; a1 += w * r[t + 256]; a2 += w * r[t + 512];
    }
  }
  size_t o = ((size_t)b * E_ + e) * D_;
  e0[o + t] = a0; e0[o + t + 256] = a1; e0[o + t + 512] = a2;
  const float* tr = trig + b * D_;
  e0t[o + t] = a0 * tr[t];
  e0t[o + t + 256] = a1 * tr[t + 256];
  e0t[o + t + 512] = a2 * tr[t + 512];
  __shared__ float red[256];
  red[t] = fabsf(a0) + fabsf(a1) + fabsf(a2);
  __syncthreads();
  for (int s2 = 128; s2 > 0; s2 >>= 1) {
    if (t < s2) red[t] += red[t + s2];
    __syncthreads();
  }
  if (t == 0) ne[b * E_ + e] = (red[0] > 0.f) ? 1.f : 0.f;
}

// ---------------- generic weighted sum: O[b,x,:] = sum_y W[b, y*sy + x*sx] * V[b,y,:] ----------------
__global__ __launch_bounds__(256) void k_wsum(const float* __restrict__ Wm, int wstride, int sy,
                                              int sx, const float* __restrict__ Vm,
                                              float* __restrict__ Om, int Y) {
  int b = blockIdx.y, x = blockIdx.x, t = threadIdx.x;
  float a0 = 0.f, a1 = 0.f, a2 = 0.f;
  const float* wb = Wm + (size_t)b * wstride + (size_t)x * sx;
  const float* vb = Vm + (size_t)b * Y * D_;
  for (int y = 0; y < Y; y++) {
    float w = wb[(size_t)y * sy];
    if (w != 0.f) {
      const float* r = vb + (size_t)y * D_;
      a0 += w * r[t]; a1 += w * r[t + 256]; a2 += w * r[t + 512];
    }
  }
  float* o = Om + ((size_t)b * gridDim.x + x) * D_;
  o[t] = a0; o[t + 256] = a1; o[t + 512] = a2;
}

// ---------------- tb[b,d] = b_ta[d] + sum_k trig[b,k]*W_ta[(D+k)*D + d] ----------------
__global__ void k_tb(const float* __restrict__ trig, const float* __restrict__ W_ta,
                     const float* __restrict__ b_ta, float* __restrict__ tb) {
  int b = blockIdx.y;
  int d = blockIdx.x * 256 + threadIdx.x;
  float acc = b_ta[d];
  for (int k = 0; k < D_; k++) acc += trig[b * D_ + k] * W_ta[(size_t)(D_ + k) * D_ + d];
  tb[b * D_ + d] = acc;
}

// ---------------- tiled fp32 GEMM: C[M,N] = sum_p A_p[M,768] @ B_p[768,N] ----------------
#define BM 64
#define BN 64
#define BK 16
__global__ __launch_bounds__(256) void k_gemm(float* __restrict__ C, int N,
                                              const float* __restrict__ A0,
                                              const float* __restrict__ B0,
                                              const float* __restrict__ A1,
                                              const float* __restrict__ B1,
                                              const float* __restrict__ A2,
                                              const float* __restrict__ B2, int npairs) {
  __shared__ float As[BK][68];
  __shared__ float Bs[BK][BN];
  int tid = threadIdx.x;
  int bx = blockIdx.x, by = blockIdx.y;
  int tx = tid & 15, ty = tid >> 4;
  float acc[4][4] = {};
  const float* Ap[3] = {A0, A1, A2};
  const float* Bp[3] = {B0, B1, B2};
  int am = tid >> 2, ak = (tid & 3) * 4;
  int bk = tid >> 4, bn = (tid & 15) * 4;
  for (int p = 0; p < npairs; p++) {
    const float* A = Ap[p];
    const float* Bm = Bp[p];
    for (int k0 = 0; k0 < D_; k0 += BK) {
      float4 av = *(const float4*)&A[((size_t)(by * BM + am)) * D_ + k0 + ak];
      float4 bv = *(const float4*)&Bm[((size_t)(k0 + bk)) * N + bx * BN + bn];
      __syncthreads();
      As[ak + 0][am] = av.x; As[ak + 1][am] = av.y;
      As[ak + 2][am] = av.z; As[ak + 3][am] = av.w;
      *(float4*)&Bs[bk][bn] = bv;
      __syncthreads();
#pragma unroll
      for (int k = 0; k < BK; k++) {
        float4 a4 = *(const float4*)&As[k][ty * 4];
        float4 b4 = *(const float4*)&Bs[k][tx * 4];
        acc[0][0] += a4.x * b4.x; acc[0][1] += a4.x * b4.y;
        acc[0][2] += a4.x * b4.z; acc[0][3] += a4.x * b4.w;
        acc[1][0] += a4.y * b4.x; acc[1][1] += a4.y * b4.y;
        acc[1][2] += a4.y * b4.z; acc[1][3] += a4.y * b4.w;
        acc[2][0] += a4.z * b4.x; acc[2][1] += a4.z * b4.y;
        acc[2][2] += a4.z * b4.z; acc[2][3] += a4.z * b4.w;
        acc[3][0] += a4.w * b4.x; acc[3][1] += a4.w * b4.y;
        acc[3][2] += a4.w * b4.z; acc[3][3] += a4.w * b4.w;
      }
    }
  }
#pragma unroll
  for (int i = 0; i < 4; i++) {
    float4 o = make_float4(acc[i][0], acc[i][1], acc[i][2], acc[i][3]);
    *(float4*)&C[((size_t)(by * BM + ty * 4 + i)) * N + bx * BN + tx * 4] = o;
  }
}

// ---------------- entity_new epilogue: (C + tb[b]) * nonempty ----------------
__global__ void k_entnew_ep(float* __restrict__ C, const float* __restrict__ tb,
                            const float* __restrict__ ne) {
  int r = blockIdx.x, t = threadIdx.x;
  int b = r >> 6;
  float m = ne[r];
  size_t o = (size_t)r * D_;
  for (int d = t; d < D_; d += 256) C[o + d] = (C[o + d] + tb[b * D_ + d]) * m;
}

// ---------------- score[b,e,a] = dot(entity_new[b,e], arg[b,a]) / sqrt(D) ----------------
__global__ __launch_bounds__(256) void k_score(const float* __restrict__ entn,
                                               const float* __restrict__ argm,
                                               float* __restrict__ score) {
  int b = blockIdx.y, e = blockIdx.x, t = threadIdx.x;
  __shared__ float ent[D_];
  const float* er = entn + ((size_t)b * E_ + e) * D_;
  for (int d = t; d < D_; d += 256) ent[d] = er[d];
  __syncthreads();
  int wave = t >> 6, lane = t & 63;
  const float scale = 0.03608439182435161f;  // 1/sqrt(768)
  for (int a = wave; a < NA_; a += 4) {
    const float* ar = argm + ((size_t)b * NA_ + a) * D_;
    float p = 0.f;
#pragma unroll
    for (int i = 0; i < 12; i++) {
      int d = lane + 64 * i;
      p += ent[d] * ar[d];
    }
    for (int off = 32; off > 0; off >>= 1) p += __shfl_down(p, off);
    if (lane == 0) score[((size_t)b * E_ + e) * NA_ + a] = p * scale;
  }
}

// ---------------- L1 normalize over a (t2a) and over e (a2t) ----------------
__global__ void k_norm(const float* __restrict__ score, float* __restrict__ t2a,
                       float* __restrict__ a2t) {
  int b = blockIdx.x, t = threadIdx.x;
  __shared__ float s[E_ * NA_];
  __shared__ float rs[E_];
  __shared__ float cs[NA_];
  for (int i = t; i < E_ * NA_; i += 256) s[i] = score[(size_t)b * E_ * NA_ + i];
  __syncthreads();
  if (t < E_) {
    float sum = 0.f;
    for (int a = 0; a < NA_; a++) sum += fabsf(s[t * NA_ + a]);
    rs[t] = fmaxf(sum, EPSF);
  } else if (t >= 64 && t < 96) {
    int a = t - 64;
    float sum = 0.f;
    for (int e = 0; e < E_; e++) sum += fabsf(s[e * NA_ + a]);
    cs[a] = fmaxf(sum, EPSF);
  }
  __syncthreads();
  for (int i = t; i < E_ * NA_; i += 256) {
    int e = i >> 5, a = i & 31;
    float v = s[i];
    t2a[(size_t)b * E_ * NA_ + i] = v / rs[e];
    a2t[(size_t)b * E_ * NA_ + i] = v / cs[a];
  }
}

// ---------------- a2a = softmax(arg @ arg^T) ----------------
__global__ __launch_bounds__(256) void k_a2a(const float* __restrict__ argm,
                                             float* __restrict__ a2a) {
  int b = blockIdx.y, a = blockIdx.x, t = threadIdx.x;
  __shared__ float sA[D_];
  __shared__ float lg[NA_];
  const float* ar = argm + ((size_t)b * NA_ + a) * D_;
  for (int d = t; d < D_; d += 256) sA[d] = ar[d];
  __syncthreads();
  int wave = t >> 6, lane = t & 63;
  for (int a2 = wave; a2 < NA_; a2 += 4) {
    const float* br = argm + ((size_t)b * NA_ + a2) * D_;
    float p = 0.f;
#pragma unroll
    for (int i = 0; i < 12; i++) {
      int d = lane + 64 * i;
      p += sA[d] * br[d];
    }
    for (int off = 32; off > 0; off >>= 1) p += __shfl_down(p, off);
    if (lane == 0) lg[a2] = p;
  }
  __syncthreads();
  if (t < 64) {
    float v = (t < NA_) ? lg[t] : -INFINITY;
    float m = v;
    for (int mask = 16; mask > 0; mask >>= 1) m = fmaxf(m, __shfl_xor(m, mask));
    float ex = (t < NA_) ? expf(v - m) : 0.f;
    float sm = ex;
    for (int mask = 16; mask > 0; mask >>= 1) sm += __shfl_xor(sm, mask);
    if (t < NA_) a2a[((size_t)b * NA_ + a) * NA_ + t] = ex / sm;
  }
}

// ---------------- t2t: gathered, head-mean, per-att row-normalized, averaged ----------------
__global__ __launch_bounds__(128) void k_t2t(const float* __restrict__ att0,
                                             const float* __restrict__ att1,
                                             const float* __restrict__ att2,
                                             const int* __restrict__ idxs,
                                             const int* __restrict__ meta,
                                             float* __restrict__ t2t) {
  int b = blockIdx.y, s = blockIdx.x, t = threadIdx.x;
  int sb = meta[b * 4 + 0];
  float* out = t2t + ((size_t)b * S_ + s) * S_;
  if (s >= sb) {
    for (int j = t; j < S_; j += 128) out[j] = 0.f;
    return;
  }
  int Is = idxs[b * WIDX_ + s];
  int It = (t < S_) ? idxs[b * WIDX_ + t] : 0;
  __shared__ float row[256];
  __shared__ float red[128];
  const float* atts[3] = {att0, att1, att2};
  float accout = 0.f;
  for (int q = 0; q < 3; q++) {
    float r0 = 0.f, r1 = 0.f;
    const float* base = atts[q] + (((size_t)b * H_) * L_ + Is) * L_;
    for (int h = 0; h < H_; h++) {
      const float* rp = base + (size_t)h * L_ * L_;
      r0 += rp[t];
      r1 += rp[t + 128];
    }
    row[t] = r0;
    row[t + 128] = r1;
    __syncthreads();
    float v = (t < sb) ? row[It] * (1.f / 12.f) : 0.f;
    red[t] = v;
    __syncthreads();
    for (int s2 = 64; s2 > 0; s2 >>= 1) {
      if (t < s2) red[t] += red[t + s2];
      __syncthreads();
    }
    float rsum = red[0];
    __syncthreads();
    accout += v / fmaxf(rsum, EPSF) * (1.f / 3.f);
  }
  if (t < S_) out[t] = accout;
}

// ---------------- final: out = gelu(Pe + Pa + b1) @ W2 + b2 ----------------
__global__ __launch_bounds__(256) void k_final(const float* __restrict__ Pe,
                                               const float* __restrict__ Pa,
                                               const float* __restrict__ b1,
                                               const float* __restrict__ W2,
                                               const float* __restrict__ b2,
                                               float* __restrict__ out) {
  int b = blockIdx.z, e = blockIdx.y, a = blockIdx.x, t = threadIdx.x;
  const float* pe = Pe + ((size_t)b * E_ + e) * NHID_;
  const float* pa = Pa + ((size_t)b * NA_ + a) * NHID_;
  float acc = 0.f;
#pragma unroll
  for (int i = 0; i < 4; i++) {
    int n = t + 256 * i;
    float x = pe[n] + pa[n] + b1[n];
    float g = 0.5f * x * (1.f + erff(x * 0.70710678118654752f));
    acc += g * W2[n];
  }
  __shared__ float red[256];
  red[t] = acc;
  __syncthreads();
  for (int s2 = 128; s2 > 0; s2 >>= 1) {
    if (t < s2) red[t] += red[t + s2];
    __syncthreads();
  }
  if (t == 0) out[((size_t)b * E_ + e) * NA_ + a] = red[0] + b2[0];
}

extern "C" void kernel_launch(void* const* d_in, const int* in_sizes, int n_in,
                              void* d_out, int out_size, void* d_ws, size_t ws_size,
                              hipStream_t stream) {
  const float* emb    = (const float*)d_in[0];
  const float* istrig = (const float*)d_in[1];
  const float* argw   = (const float*)d_in[2];
  const float* entmap = (const float*)d_in[3];
  const float* att0   = (const float*)d_in[4];
  const float* att1   = (const float*)d_in[5];
  const float* att2   = (const float*)d_in[6];
  const float* W_ta   = (const float*)d_in[7];
  const float* b_ta   = (const float*)d_in[8];
  const float* W1     = (const float*)d_in[9];
  const float* b1     = (const float*)d_in[10];
  const float* W2     = (const float*)d_in[11];
  const float* b2     = (const float*)d_in[12];
  const int*   idxs   = (const int*)d_in[13];
  const int*   blen   = (const int*)d_in[14];
  float* out = (float*)d_out;

  float* ws = (float*)d_ws;
  size_t o = 0;
  int* meta = (int*)ws; o += 256;
  float* sent_emb = ws + o; o += (size_t)B_ * S_ * D_;
  float* arg_emb  = ws + o; o += (size_t)B_ * LA_ * D_;
  float* trig     = ws + o; o += (size_t)B_ * D_;
  float* e0       = ws + o; o += (size_t)B_ * E_ * D_;
  float* e0t      = ws + o; o += (size_t)B_ * E_ * D_;
  float* argm     = ws + o; o += (size_t)B_ * NA_ * D_;
  float* entn     = ws + o; o += (size_t)B_ * E_ * D_;
  float* tb       = ws + o; o += (size_t)B_ * D_;
  float* ne       = ws + o; o += (size_t)B_ * E_;
  float* score    = ws + o; o += (size_t)B_ * E_ * NA_;
  float* t2a      = ws + o; o += (size_t)B_ * E_ * NA_;
  float* a2t      = ws + o; o += (size_t)B_ * E_ * NA_;
  float* t2t      = ws + o; o += (size_t)B_ * S_ * S_;
  float* ah2h     = ws + o; o += (size_t)B_ * S_ * D_;
  float* Ah2h     = ws + o; o += (size_t)B_ * E_ * D_;
  float* tokA     = ws + o; o += (size_t)B_ * E_ * D_;
  float* argTok   = ws + o; o += (size_t)B_ * NA_ * D_;
  float* a2a      = ws + o; o += (size_t)B_ * NA_ * NA_;
  float* Au2u     = ws + o; o += (size_t)B_ * NA_ * D_;
  float* Pe       = ws + o; o += (size_t)B_ * E_ * NHID_;
  float* Pa       = ws + o; o += (size_t)B_ * NA_ * NHID_;

  k_meta<<<B_, 128, 0, stream>>>(idxs, blen, meta);
  k_gather<<<dim3(S_ + LA_, B_), 256, 0, stream>>>(emb, idxs, meta, sent_emb, arg_emb);
  k_trig<<<dim3(3, B_), 256, 0, stream>>>(sent_emb, istrig, trig);
  k_entity0<<<dim3(E_, B_), 256, 0, stream>>>(sent_emb, entmap, trig, e0, e0t, ne);
  k_wsum<<<dim3(NA_, B_), 256, 0, stream>>>(argw, LA_ * NA_, NA_, 1, arg_emb, argm, LA_);
  k_tb<<<dim3(3, B_), 256, 0, stream>>>(trig, W_ta, b_ta, tb);

  // entity_new = e0 @ W_ta[0:D] + e0t @ W_ta[2D:3D]   (trig term + bias in tb)
  k_gemm<<<dim3(D_ / BN, (B_ * E_) / BM), 256, 0, stream>>>(
      entn, D_, e0, W_ta, e0t, W_ta + (size_t)2 * D_ * D_, e0, W_ta, 2);
  k_entnew_ep<<<B_ * E_, 256, 0, stream>>>(entn, tb, ne);

  k_score<<<dim3(E_, B_), 256, 0, stream>>>(entn, argm, score);
  k_norm<<<B_, 256, 0, stream>>>(score, t2a, a2t);
  k_wsum<<<dim3(E_, B_), 256, 0, stream>>>(t2a, E_ * NA_, 1, NA_, argm, tokA, NA_);
  k_wsum<<<dim3(NA_, B_), 256, 0, stream>>>(a2t, E_ * NA_, NA_, 1, entn, argTok, E_);
  k_a2a<<<dim3(NA_, B_), 256, 0, stream>>>(argm, a2a);
  k_wsum<<<dim3(NA_, B_), 256, 0, stream>>>(a2a, NA_ * NA_, 1, NA_, argm, Au2u, NA_);

  k_t2t<<<dim3(S_, B_), 128, 0, stream>>>(att0, att1, att2, idxs, meta, t2t);
  k_wsum<<<dim3(S_, B_), 256, 0, stream>>>(t2t, S_ * S_, 1, S_, sent_emb, ah2h, S_);
  k_wsum<<<dim3(E_, B_), 256, 0, stream>>>(entmap, S_ * E_, E_, 1, ah2h, Ah2h, S_);

  // P_e = H_ @ W1[0:D] + tokA @ W1[2D:3D] + Ah2h @ W1[3D:4D]
  k_gemm<<<dim3(NHID_ / BN, (B_ * E_) / BM), 256, 0, stream>>>(
      Pe, NHID_, e0, W1, tokA, W1 + (size_t)2 * D_ * NHID_, Ah2h, W1 + (size_t)3 * D_ * NHID_, 3);
  // P_a = arg @ W1[D:2D] + argTok @ W1[4D:5D] + Au2u @ W1[5D:6D]
  k_gemm<<<dim3(NHID_ / BN, (B_ * NA_) / BM), 256, 0, stream>>>(
      Pa, NHID_, argm, W1 + (size_t)D_ * NHID_, argTok, W1 + (size_t)4 * D_ * NHID_, Au2u,
      W1 + (size_t)5 * D_ * NHID_, 3);

  k_final<<<dim3(NA_, E_, B_), 256, 0, stream>>>(Pe, Pa, b1, W2, b2, out);
}